// Round 11
// baseline (671.313 us; speedup 1.0000x reference)
//
#include <hip/hip_runtime.h>
#include <hip/hip_bf16.h>

// ToyMDNN on MI355X — round 11: occupancy fix for the GEMMs.
//  * r10 counters: gemm_qkvs 89us, Occupancy 18.9% (76.8KB LDS -> 2 blk/CU),
//    2.6 TB/s — BW-efficiency-bound by residency.
//  * qkvs: weight dbuf at HALF-matrix granularity (2x16KB), reg-prefetch ->
//    write-other-buffer -> 1 barrier/stage (8 stages x 16 MFMA); stats
//    scratch overlaid on the bounce tile. LDS 40KB -> 4 blocks/CU,
//    __launch_bounds__(256,4).
//  * gemm_one: half-tile bounce (8KB) + stats overlay -> 40KB, 4 blocks/CU.
//  * all arithmetic unchanged -> output bit-identical to r10 (absmax .1445).
// N=1024 S=128 D=128 H=4 C=32 L=2. GEMM biases cancel through batch-norm.

typedef __attribute__((ext_vector_type(8))) short short8v;
typedef __attribute__((ext_vector_type(16))) float f32x16;

#define NBATCH 1024
#define SEQ    128
#define DIM    128
#define NLAYER 2
#define MTOT   (NBATCH*SEQ)
#define EPSF   1e-5f
#define INV_M  (1.0f/131072.0f)
#define HM32   ((long)MTOT * 32)     // head-major per-head region (elements)

__device__ __forceinline__ float bf2f(ushort s) {
  return __uint_as_float(((uint)s) << 16);
}
__device__ __forceinline__ ushort f2bf(float f) {
  uint u = __float_as_uint(f);
  return (ushort)((u + 0x7FFFu + ((u >> 16) & 1u)) >> 16);
}

struct WPtrs { const float* p[11]; };

// ---------------------------------------------------------------------------
// One-time: 11 weight matrices fp32 -> bf16 packed in B-fragment order:
// dst[m*16384 + kc*1024 + nt*256 + ln*8 + i] = W[nt*32+ln][kc*8+i].
// ---------------------------------------------------------------------------
__global__ __launch_bounds__(256) void prep_w(WPtrs wp, ushort* __restrict__ dst)
{
  const int gid = blockIdx.x * 256 + threadIdx.x;   // 88*256 = 11*2048
  const int m = gid >> 11;
  const int rem = gid & 2047;
  const int j = rem >> 4, kc = rem & 15;
  const float* src = wp.p[m];
  float4 a = *(const float4*)(src + j * DIM + kc * 8);
  float4 b = *(const float4*)(src + j * DIM + kc * 8 + 4);
  short8v v;
  v[0] = (short)f2bf(a.x); v[1] = (short)f2bf(a.y);
  v[2] = (short)f2bf(a.z); v[3] = (short)f2bf(a.w);
  v[4] = (short)f2bf(b.x); v[5] = (short)f2bf(b.y);
  v[6] = (short)f2bf(b.z); v[7] = (short)f2bf(b.w);
  const int nt = j >> 5, ln = j & 31;
  *(short8v*)(dst + m * 16384 + kc * 1024 + nt * 256 + ln * 8) = v;
}

// ---------------------------------------------------------------------------
// One-time: pack 0/1 fp32 mask rows into 128-bit rows (uint4).
// ---------------------------------------------------------------------------
__global__ __launch_bounds__(256) void pack_mask(
    const float* __restrict__ mask, uint4* __restrict__ mb)
{
  const int lane = threadIdx.x & 63;
  const int wv   = (blockIdx.x * 256 + threadIdx.x) >> 6;
  const int NW   = gridDim.x * 4;
  for (int row = wv; row < MTOT; row += NW) {
    const float a = mask[(long)row * SEQ + lane];
    const float b = mask[(long)row * SEQ + 64 + lane];
    const unsigned long long lo = __ballot(a != 0.f);
    const unsigned long long hi = __ballot(b != 0.f);
    if (lane == 0) {
      uint4 w;
      w.x = (uint)lo; w.y = (uint)(lo >> 32);
      w.z = (uint)hi; w.w = (uint)(hi >> 32);
      mb[row] = w;
    }
  }
}

// ---------------------------------------------------------------------------
// Single GEMM: out[m][j] = sum_k A[m][k]*W[j][k] + column stats.
// W staged once into LDS. Half-tile bounce (8KB) + stats overlay -> 40KB LDS,
// 4 blocks/CU. OM=0: out fp32 [M][128]; OM=1: out fp32 head-major.
// ---------------------------------------------------------------------------
template<int OM>
__global__ __launch_bounds__(256, 4) void gemm_one(
    const float* __restrict__ A, const ushort* __restrict__ Wm,
    float* __restrict__ outp, float* __restrict__ stats)
{
  __shared__ ushort Wl[16384];       // 32 KB staged weights
  __shared__ float tb[4][512];       // 8 KB half-tile bounce; stats overlay
  const int tid = threadIdx.x;
  const int lane = tid & 63, wid = tid >> 6;
  const int hi = lane >> 5, ln = lane & 31;
  const long m0 = (long)blockIdx.x * 128;
  const long arow = m0 + wid * 32 + ln;

  // stage W (coalesced 16B copy)
#pragma unroll
  for (int i = 0; i < 8; ++i)
    ((short8v*)Wl)[i * 256 + tid] = ((const short8v*)Wm)[i * 256 + tid];

  short8v afr[8];
  {
    const float* ar = A + arow * DIM + hi * 8;
#pragma unroll
    for (int kt = 0; kt < 8; ++kt) {
      float4 a0 = *(const float4*)(ar + kt * 16);
      float4 a1 = *(const float4*)(ar + kt * 16 + 4);
      short8v v;
      v[0] = (short)f2bf(a0.x); v[1] = (short)f2bf(a0.y);
      v[2] = (short)f2bf(a0.z); v[3] = (short)f2bf(a0.w);
      v[4] = (short)f2bf(a1.x); v[5] = (short)f2bf(a1.y);
      v[6] = (short)f2bf(a1.z); v[7] = (short)f2bf(a1.w);
      afr[kt] = v;
    }
  }
  __syncthreads();

  f32x16 acc[4];
#pragma unroll
  for (int nt = 0; nt < 4; ++nt)
#pragma unroll
    for (int r = 0; r < 16; ++r) acc[nt][r] = 0.f;

#pragma unroll
  for (int kt = 0; kt < 8; ++kt) {
    const ushort* wb = Wl + (kt * 2 + hi) * 1024 + ln * 8;
#pragma unroll
    for (int nt = 0; nt < 4; ++nt) {
      short8v b = *(const short8v*)(wb + nt * 256);
      acc[nt] = __builtin_amdgcn_mfma_f32_32x32x16_bf16(afr[kt], b, acc[nt], 0, 0, 0);
    }
  }

  float ps[4], pq[4];
#pragma unroll
  for (int nt = 0; nt < 4; ++nt) { ps[nt] = 0.f; pq[nt] = 0.f; }

#pragma unroll
  for (int nt = 0; nt < 4; ++nt) {
#pragma unroll
    for (int h2 = 0; h2 < 2; ++h2) {      // half-tile: rows h2*16 .. +15
#pragma unroll
      for (int rr = 0; rr < 8; ++rr) {
        const int r = h2 * 8 + rr;
        const float v = acc[nt][r];
        ps[nt] += v; pq[nt] += v * v;
        const int lrow = (rr & 3) + 8 * (rr >> 2) + 4 * hi;   // 0..15
        tb[wid][lrow * 32 + ln] = v;
      }
      if constexpr (OM == 0) {
#pragma unroll
        for (int i = 0; i < 2; ++i) {
          const int lrow = i * 8 + (lane >> 3);
          float4 v = *(const float4*)&tb[wid][lrow * 32 + (lane & 7) * 4];
          *(float4*)(outp + (m0 + wid * 32 + h2 * 16 + lrow) * DIM + nt * 32 + (lane & 7) * 4) = v;
        }
      } else {
        float* dst = outp + (long)nt * HM32 + (m0 + wid * 32 + h2 * 16) * 32;
#pragma unroll
        for (int i = 0; i < 2; ++i) {
          float4 v = *(const float4*)&tb[wid][i * 256 + lane * 4];
          *(float4*)(dst + i * 256 + lane * 4) = v;
        }
      }
    }
  }

#pragma unroll
  for (int nt = 0; nt < 4; ++nt) {
    ps[nt] += __shfl_xor(ps[nt], 32);
    pq[nt] += __shfl_xor(pq[nt], 32);
  }
  // stats overlay on tb (256 floats)
  float* cs = (float*)tb;
  __syncthreads();
  if (tid < 256) cs[tid] = 0.f;
  __syncthreads();
  if (hi == 0) {
#pragma unroll
    for (int nt = 0; nt < 4; ++nt) {
      atomicAdd(&cs[nt * 32 + ln], ps[nt]);
      atomicAdd(&cs[128 + nt * 32 + ln], pq[nt]);
    }
  }
  __syncthreads();
  if (tid < 128) {
    atomicAdd(&stats[tid],       cs[tid]);
    atomicAdd(&stats[128 + tid], cs[128 + tid]);
  }
}

// ---------------------------------------------------------------------------
// Fused Q/K/V/SKIP GEMM. A read once; weights pipelined through a 2x16KB
// HALF-matrix LDS dbuf (reg-prefetch next half before MFMA, write into the
// other buffer, 1 barrier/stage; 8 stages x 16 MFMA). Stats scratch overlaid
// on the bounce tile. LDS 40KB -> 4 blocks/CU.
// ---------------------------------------------------------------------------
__global__ __launch_bounds__(256, 4) void gemm_qkvs(
    const float* __restrict__ A, const ushort* __restrict__ wbase,
    ushort* __restrict__ o0, ushort* __restrict__ o1,
    ushort* __restrict__ o2, ushort* __restrict__ o3,
    float* __restrict__ st0, float* __restrict__ st1,
    float* __restrict__ st2, float* __restrict__ st3)
{
  __shared__ ushort wbuf[2][8192];       // 2 x 16KB half-matrix dbuf
  __shared__ ushort qtb[4][1024];        // 8KB bounce; stats overlay (4KB)
  const int tid = threadIdx.x;
  const int lane = tid & 63, wid = tid >> 6;
  const int hi = lane >> 5, ln = lane & 31;
  const long m0 = (long)blockIdx.x * 128;
  const long arow = m0 + wid * 32 + ln;

  short8v afr[8];
  {
    const float* ar = A + arow * DIM + hi * 8;
#pragma unroll
    for (int kt = 0; kt < 8; ++kt) {
      float4 a0 = *(const float4*)(ar + kt * 16);
      float4 a1 = *(const float4*)(ar + kt * 16 + 4);
      short8v v;
      v[0] = (short)f2bf(a0.x); v[1] = (short)f2bf(a0.y);
      v[2] = (short)f2bf(a0.z); v[3] = (short)f2bf(a0.w);
      v[4] = (short)f2bf(a1.x); v[5] = (short)f2bf(a1.y);
      v[6] = (short)f2bf(a1.z); v[7] = (short)f2bf(a1.w);
      afr[kt] = v;
    }
  }

  // stage half 0 of w0
#pragma unroll
  for (int i = 0; i < 4; ++i)
    ((short8v*)wbuf[0])[i * 256 + tid] = ((const short8v*)wbase)[i * 256 + tid];

  float ps[4][4], pq[4][4];
#pragma unroll
  for (int w = 0; w < 4; ++w)
#pragma unroll
    for (int nt = 0; nt < 4; ++nt) { ps[w][nt] = 0.f; pq[w][nt] = 0.f; }

  f32x16 acc[4];
  __syncthreads();

  const int wofl[4] = {0, 1, 2, 4};      // q,k,v,skip matrix offsets

#pragma unroll
  for (int s = 0; s < 8; ++s) {
    const int w = s >> 1, half = s & 1;

    // prefetch next half-matrix into registers (global loads issue now)
    short8v nw[4];
    if (s < 7) {
      const int ns = s + 1;
      const short8v* src = (const short8v*)(wbase + wofl[ns >> 1] * 16384 + (ns & 1) * 8192);
#pragma unroll
      for (int i = 0; i < 4; ++i) nw[i] = src[i * 256 + tid];
    }

    if (half == 0) {
#pragma unroll
      for (int nt = 0; nt < 4; ++nt)
#pragma unroll
        for (int r = 0; r < 16; ++r) acc[nt][r] = 0.f;
    }

    const ushort* wt = wbuf[s & 1];
#pragma unroll
    for (int ktl = 0; ktl < 4; ++ktl) {
      const int kt = half * 4 + ktl;
      const ushort* wb = wt + (ktl * 2 + hi) * 1024 + ln * 8;
#pragma unroll
      for (int nt = 0; nt < 4; ++nt) {
        short8v b = *(const short8v*)(wb + nt * 256);
        acc[nt] = __builtin_amdgcn_mfma_f32_32x32x16_bf16(afr[kt], b, acc[nt], 0, 0, 0);
      }
    }

    // write prefetched half into the OTHER buffer (its readers finished at
    // the end of stage s-1; no extra barrier needed)
    if (s < 7) {
      short8v* dst = (short8v*)wbuf[(s + 1) & 1];
#pragma unroll
      for (int i = 0; i < 4; ++i) dst[i * 256 + tid] = nw[i];
    }

    if (half == 1) {
      // bounce-store w's output (head-major, 16B/lane coalesced)
      ushort* outp = (w == 0) ? o0 : (w == 1) ? o1 : (w == 2) ? o2 : o3;
#pragma unroll
      for (int nt = 0; nt < 4; ++nt) {
#pragma unroll
        for (int r = 0; r < 16; ++r) {
          const float v = acc[nt][r];
          ps[w][nt] += v; pq[w][nt] += v * v;
          const int row = (r & 3) + 8 * (r >> 2) + 4 * hi;
          qtb[wid][row * 32 + ln] = f2bf(v);
        }
        ushort* dst = outp + (long)nt * HM32 + (m0 + wid * 32) * 32;
        short8v v0 = *(const short8v*)&qtb[wid][lane * 8];
        short8v v1 = *(const short8v*)&qtb[wid][512 + lane * 8];
        *(short8v*)(dst + lane * 8)       = v0;
        *(short8v*)(dst + 512 + lane * 8) = v1;
      }
    }
    __syncthreads();
  }

  // stats epilogue, overlaid on qtb: cs[w*256 + c]=sum, cs[w*256+128+c]=sumsq
  float* cs = (float*)qtb;
  cs[tid] = 0.f; cs[256 + tid] = 0.f; cs[512 + tid] = 0.f; cs[768 + tid] = 0.f;
  __syncthreads();
#pragma unroll
  for (int w = 0; w < 4; ++w) {
    float lps[4], lpq[4];
#pragma unroll
    for (int nt = 0; nt < 4; ++nt) {
      lps[nt] = ps[w][nt] + __shfl_xor(ps[w][nt], 32);
      lpq[nt] = pq[w][nt] + __shfl_xor(pq[w][nt], 32);
    }
    if (hi == 0) {
#pragma unroll
      for (int nt = 0; nt < 4; ++nt) {
        atomicAdd(&cs[w * 256 + nt * 32 + ln], lps[nt]);
        atomicAdd(&cs[w * 256 + 128 + nt * 32 + ln], lpq[nt]);
      }
    }
  }
  __syncthreads();
  if (tid < 128) {
    atomicAdd(&st0[tid],       cs[tid]);
    atomicAdd(&st0[128 + tid], cs[128 + tid]);
    atomicAdd(&st1[tid],       cs[256 + tid]);
    atomicAdd(&st1[128 + tid], cs[384 + tid]);
    atomicAdd(&st2[tid],       cs[512 + tid]);
    atomicAdd(&st2[128 + tid], cs[640 + tid]);
    atomicAdd(&st3[tid],       cs[768 + tid]);
    atomicAdd(&st3[128 + tid], cs[896 + tid]);
  }
}

// ---------------------------------------------------------------------------
// In-place BN apply for h (fp32).
// ---------------------------------------------------------------------------
__global__ __launch_bounds__(256) void bn_apply(
    float* __restrict__ x, const float* __restrict__ st,
    const float* __restrict__ g, const float* __restrict__ b)
{
  __shared__ float sc[128], bi[128];
  const int tid = threadIdx.x;
  if (tid < 128) {
    float mean = st[tid] * INV_M;
    float var  = st[128 + tid] * INV_M - mean * mean;
    float s = rsqrtf(var + EPSF) * g[tid];
    sc[tid] = s;
    bi[tid] = b[tid] - mean * s;
  }
  __syncthreads();
  const long total4 = (long)MTOT * DIM / 4;
  for (long i = (long)blockIdx.x * 256 + tid; i < total4; i += (long)gridDim.x * 256) {
    float4 vv = ((const float4*)x)[i];
    const int c = (int)((i * 4) & 127);
    vv.x = vv.x * sc[c + 0] + bi[c + 0];
    vv.y = vv.y * sc[c + 1] + bi[c + 1];
    vv.z = vv.z * sc[c + 2] + bi[c + 2];
    vv.w = vv.w * sc[c + 3] + bi[c + 3];
    ((float4*)x)[i] = vv;
  }
}

// ---------------------------------------------------------------------------
// Attention + fused LN(agg+h). One block per n; wave = head.
// S^T = mfma(K,Q) -> in-lane softmax; PV from D-regs; V BN folded via
// sum(P)=1; y = vs*o+vb0 + h (fp32); LN across waves via LDS reduce;
// out1 written FP32 IN-PLACE over h ([M][128]).
// ---------------------------------------------------------------------------
__global__ __launch_bounds__(256, 4) void attn_ln(
    const ushort* __restrict__ q, const ushort* __restrict__ k_in,
    const ushort* __restrict__ v_in,
    float* hbuf,                      // h in, out1 out (aliased on purpose)
    const uint4* __restrict__ mb,
    const float* __restrict__ qst, const float* __restrict__ kst, const float* __restrict__ vst,
    const float* __restrict__ qg, const float* __restrict__ qbb,
    const float* __restrict__ kg, const float* __restrict__ kbb,
    const float* __restrict__ vg, const float* __restrict__ vbb,
    const float* __restrict__ lng, const float* __restrict__ lnb)
{
  __shared__ ushort Vp[128 * 136];          // [c_global][slot(t)]
  __shared__ float qsc[128], qbi[128], ksc[128], kbi[128];
  __shared__ float reds[32][4], redq[32][4];
  __shared__ float2 rmv[32];

  const int tid = threadIdx.x;
  const int lane = tid & 63, hh = tid >> 6;
  const int hi = lane >> 5, ln = lane & 31;
  const int n = blockIdx.x;
  const long nb = (long)n * SEQ;            // global row base
  const long hbase = (long)hh * HM32 + nb * 32;

  if (tid < 128) {
    const int c = tid;
    float m, v, s;
    m = qst[c] * INV_M; v = qst[128 + c] * INV_M - m * m;
    s = rsqrtf(v + EPSF) * qg[c];  qsc[c] = s; qbi[c] = qbb[c] - m * s;
    m = kst[c] * INV_M; v = kst[128 + c] * INV_M - m * m;
    s = rsqrtf(v + EPSF) * kg[c];  ksc[c] = s; kbi[c] = kbb[c] - m * s;
  }
  const int cg = hh * 32 + ln;              // global output column
  float vs, vb0;
  {
    float m = vst[cg] * INV_M;
    float v = vst[128 + cg] * INV_M - m * m;
    vs = rsqrtf(v + EPSF) * vg[cg];
    vb0 = vbb[cg] - m * vs;
  }
  const float lgc = lng[cg], lbc = lnb[cg];

  // stage own head's V slice (dense 8KB) into permuted slots
#pragma unroll
  for (int it = 0; it < 8; ++it) {
    const int t = it * 16 + (lane >> 2);
    const int c0 = (lane & 3) * 8;
    short8v vv = *(const short8v*)(v_in + hbase + (long)t * 32 + c0);
    const int tl = t & 31;
    const int kt = tl >> 4;
    const int rem = tl & 15;
    const int slot = (t & 96) + (kt << 4) + ((rem >> 2) & 1) * 8 + ((rem & 3) | (((rem >> 3) & 1) << 2));
#pragma unroll
    for (int i = 0; i < 8; ++i) Vp[(hh * 32 + c0 + i) * 136 + slot] = (ushort)vv[i];
  }
  __syncthreads();

  // normalized K fragments, cached for all row-tiles
  short8v kfr[4][2];
#pragma unroll
  for (int nt = 0; nt < 4; ++nt)
#pragma unroll
    for (int kt = 0; kt < 2; ++kt) {
      short8v raw = *(const short8v*)(k_in + hbase + (long)(nt * 32 + ln) * 32 + kt * 16 + hi * 8);
      short8v f;
#pragma unroll
      for (int i = 0; i < 8; ++i) {
        const int c = hh * 32 + kt * 16 + hi * 8 + i;
        f[i] = (short)f2bf(bf2f((ushort)raw[i]) * ksc[c] + kbi[c]);
      }
      kfr[nt][kt] = f;
    }

  for (int mt = 0; mt < 4; ++mt) {
    // normalized Q fragments (B operand): col s = mt*32+ln
    short8v qfr[2];
#pragma unroll
    for (int kt = 0; kt < 2; ++kt) {
      short8v raw = *(const short8v*)(q + hbase + (long)(mt * 32 + ln) * 32 + kt * 16 + hi * 8);
      short8v f;
#pragma unroll
      for (int i = 0; i < 8; ++i) {
        const int c = hh * 32 + kt * 16 + hi * 8 + i;
        f[i] = (short)f2bf(bf2f((ushort)raw[i]) * qsc[c] + qbi[c]);
      }
      qfr[kt] = f;
    }

    f32x16 st[4];
#pragma unroll
    for (int nt = 0; nt < 4; ++nt)
#pragma unroll
      for (int r = 0; r < 16; ++r) st[nt][r] = 0.f;
#pragma unroll
    for (int nt = 0; nt < 4; ++nt) {
      st[nt] = __builtin_amdgcn_mfma_f32_32x32x16_bf16(kfr[nt][0], qfr[0], st[nt], 0, 0, 0);
      st[nt] = __builtin_amdgcn_mfma_f32_32x32x16_bf16(kfr[nt][1], qfr[1], st[nt], 0, 0, 0);
    }

    // mask + in-lane softmax (softmax(alpha*mask) semantics)
    const uint4 bw = mb[nb + mt * 32 + ln];
    float mx = -1e30f;
#pragma unroll
    for (int nt = 0; nt < 4; ++nt) {
      const uint word = (nt == 0) ? bw.x : (nt == 1) ? bw.y : (nt == 2) ? bw.z : bw.w;
#pragma unroll
      for (int r = 0; r < 16; ++r) {
        const int crow = (r & 3) + 8 * (r >> 2) + 4 * hi;
        st[nt][r] = ((word >> crow) & 1u) ? st[nt][r] : 0.f;
        mx = fmaxf(mx, st[nt][r]);
      }
    }
    mx = fmaxf(mx, __shfl_xor(mx, 32));
    float sum = 0.f;
#pragma unroll
    for (int nt = 0; nt < 4; ++nt)
#pragma unroll
      for (int r = 0; r < 16; ++r) {
        const float e = __expf(st[nt][r] - mx);
        st[nt][r] = e;
        sum += e;
      }
    sum += __shfl_xor(sum, 32);
    const float inv = 1.f / sum;

    // O = P · V_raw
    f32x16 o;
#pragma unroll
    for (int r = 0; r < 16; ++r) o[r] = 0.f;
#pragma unroll
    for (int nt = 0; nt < 4; ++nt) {
#pragma unroll
      for (int kt = 0; kt < 2; ++kt) {
        short8v pa;
#pragma unroll
        for (int j = 0; j < 8; ++j) pa[j] = (short)f2bf(st[nt][kt * 8 + j] * inv);
        short8v vb = *(const short8v*)&Vp[(long)cg * 136 + nt * 32 + kt * 16 + hi * 8];
        o = __builtin_amdgcn_mfma_f32_32x32x16_bf16(pa, vb, o, 0, 0, 0);
      }
    }

    // y = BN_v-folded agg + h  (fp32)
    float yv[16];
#pragma unroll
    for (int r = 0; r < 16; ++r) {
      const int sl = (r & 3) + 8 * (r >> 2) + 4 * hi;
      const float hval = hbuf[(nb + mt * 32 + sl) * DIM + cg];
      yv[r] = vs * o[r] + vb0 + hval;
    }

    // LN across full row: intra-half butterfly + cross-wave LDS reduce
#pragma unroll
    for (int r = 0; r < 16; ++r) {
      float s = yv[r], q2 = yv[r] * yv[r];
      s += __shfl_xor(s, 1);  q2 += __shfl_xor(q2, 1);
      s += __shfl_xor(s, 2);  q2 += __shfl_xor(q2, 2);
      s += __shfl_xor(s, 4);  q2 += __shfl_xor(q2, 4);
      s += __shfl_xor(s, 8);  q2 += __shfl_xor(q2, 8);
      s += __shfl_xor(s, 16); q2 += __shfl_xor(q2, 16);
      if (ln == 0) {
        const int sl = (r & 3) + 8 * (r >> 2) + 4 * hi;
        reds[sl][hh] = s; redq[sl][hh] = q2;
      }
    }
    __syncthreads();
    if (tid < 32) {
      const float s  = reds[tid][0] + reds[tid][1] + reds[tid][2] + reds[tid][3];
      const float q2 = redq[tid][0] + redq[tid][1] + redq[tid][2] + redq[tid][3];
      const float mean = s * (1.f / 128.f);
      const float var  = q2 * (1.f / 128.f) - mean * mean;
      rmv[tid] = make_float2(mean, rsqrtf(var + EPSF));
    }
    __syncthreads();
    // out1 fp32 in-place over h
#pragma unroll
    for (int r = 0; r < 16; ++r) {
      const int sl = (r & 3) + 8 * (r >> 2) + 4 * hi;
      const float2 mr = rmv[sl];
      hbuf[(nb + mt * 32 + sl) * DIM + cg] = (yv[r] - mr.x) * mr.y * lgc + lbc;
    }
  }
}

// ---------------------------------------------------------------------------
// h_new = LN(out1 + BN_ff(ff_raw)) + BN_skip(skip_raw).
// t1 (out1) fp32 [M][128]; ffr fp32 HEAD-MAJOR; skr bf16 HEAD-MAJOR.
// Non-final: out == t1 (in-place). FINAL: rows m=n*S -> d_out (N,128).
// ---------------------------------------------------------------------------
template <bool FINAL>
__global__ __launch_bounds__(256) void fuse2_k(
    const float* t1, const float* __restrict__ ffr, const ushort* __restrict__ skr,
    const float* __restrict__ fst, const float* __restrict__ sst,
    const float* __restrict__ fg, const float* __restrict__ fb,
    const float* __restrict__ sg, const float* __restrict__ sb,
    const float* __restrict__ lg, const float* __restrict__ lb,
    float* out)
{
  const int lane = threadIdx.x & 63;
  const int c = lane * 2;
  float fs0, fbias0, fs1, fbias1, ss0, sbias0, ss1, sbias1;
  {
    float m0 = fst[c] * INV_M;
    float v0 = fst[128 + c] * INV_M - m0 * m0;
    fs0 = rsqrtf(v0 + EPSF) * fg[c];       fbias0 = fb[c] - m0 * fs0;
    float m1 = fst[c + 1] * INV_M;
    float v1 = fst[128 + c + 1] * INV_M - m1 * m1;
    fs1 = rsqrtf(v1 + EPSF) * fg[c + 1];   fbias1 = fb[c + 1] - m1 * fs1;
    float n0 = sst[c] * INV_M;
    float w0 = sst[128 + c] * INV_M - n0 * n0;
    ss0 = rsqrtf(w0 + EPSF) * sg[c];       sbias0 = sb[c] - n0 * ss0;
    float n1 = sst[c + 1] * INV_M;
    float w1 = sst[128 + c + 1] * INV_M - n1 * n1;
    ss1 = rsqrtf(w1 + EPSF) * sg[c + 1];   sbias1 = sb[c + 1] - n1 * ss1;
  }
  const float lg0 = lg[c], lg1 = lg[c + 1], lb0 = lb[c], lb1 = lb[c + 1];
  const int wid = (blockIdx.x * 256 + threadIdx.x) >> 6;
  const int NW  = gridDim.x * 4;
  const int ROWS = FINAL ? NBATCH : MTOT;
  const long thm = (long)(c >> 5) * HM32;       // head region of cols c, c+1
  for (int r = wid; r < ROWS; r += NW) {
    const long m   = FINAL ? (long)r * SEQ : (long)r;
    const long off = m * DIM + c;
    const long hm  = thm + m * 32 + (c & 31);
    float2 tv = *(const float2*)(t1 + off);
    float2 fv = *(const float2*)(ffr + hm);
    uint sv = *(const uint*)(skr + hm);
    float s0 = bf2f((ushort)(sv & 0xFFFFu)), s1 = bf2f((ushort)(sv >> 16));
    float y0 = tv.x + fv.x * fs0 + fbias0;
    float y1 = tv.y + fv.y * fs1 + fbias1;
    float s = y0 + y1, sq = y0 * y0 + y1 * y1;
#pragma unroll
    for (int o = 32; o; o >>= 1) { s += __shfl_xor(s, o); sq += __shfl_xor(sq, o); }
    const float mean = s * (1.f / 128.f);
    const float var  = sq * (1.f / 128.f) - mean * mean;
    const float rs   = rsqrtf(var + EPSF);
    float o0 = (y0 - mean) * rs * lg0 + lb0 + (s0 * ss0 + sbias0);
    float o1 = (y1 - mean) * rs * lg1 + lb1 + (s1 * ss1 + sbias1);
    const long ooff = FINAL ? ((long)r * DIM + c) : off;
    *(float2*)(out + ooff) = make_float2(o0, o1);
  }
}

// ---------------------------------------------------------------------------
extern "C" void kernel_launch(void* const* d_in, const int* in_sizes, int n_in,
                              void* d_out, int out_size, void* d_ws, size_t ws_size,
                              hipStream_t stream)
{
  (void)in_sizes; (void)n_in; (void)out_size; (void)ws_size;
  const float* x    = (const float*)d_in[0];
  const float* mask = (const float*)d_in[1];
  const float* linW = (const float*)d_in[2];
  const float* ing  = (const float*)d_in[4];
  const float* inb  = (const float*)d_in[5];
  const float* qW   = (const float*)d_in[6];
  const float* qg   = (const float*)d_in[8];
  const float* qb   = (const float*)d_in[9];
  const float* kW   = (const float*)d_in[10];
  const float* kg   = (const float*)d_in[12];
  const float* kb   = (const float*)d_in[13];
  const float* vW   = (const float*)d_in[14];
  const float* vg   = (const float*)d_in[16];
  const float* vb   = (const float*)d_in[17];
  const float* lng  = (const float*)d_in[18];
  const float* lnb  = (const float*)d_in[19];
  const float* ffW  = (const float*)d_in[20];
  const float* ffg  = (const float*)d_in[22];
  const float* ffb  = (const float*)d_in[23];
  const float* skW  = (const float*)d_in[24];
  const float* skg  = (const float*)d_in[26];
  const float* skb  = (const float*)d_in[27];

  const long MD = (long)MTOT * DIM;
  float*  stats = (float*)d_ws;                 // 11*256 floats
  float*  h     = (float*)d_ws + 4096;          // fp32 [M][128]; also out1/h_next
  ushort* qbuf  = (ushort*)(h + MD);            // bf16 head-major q
  ushort* kbuf  = qbuf + MD;                    // bf16 head-major k
  ushort* vbuf  = kbuf + MD;                    // bf16 head-major v
  ushort* sbuf  = vbuf + MD;                    // bf16 head-major skip_raw
  uint4*  mbits = (uint4*)(sbuf + MD);          // 2 MB; total ~194 MB
  float*  ffbuf = (float*)qbuf;                 // fp32 head-major ff over dead q+k

  ushort* Wsw = (ushort*)d_out;                 // 352 KB of 512 KB; final
                                                // fuse2<true> overwrites all.
  hipMemsetAsync(stats, 0, 11 * 256 * sizeof(float), stream);

  WPtrs wp;
  wp.p[0] = linW;
  wp.p[1] = qW;            wp.p[2] = kW;            wp.p[3] = vW;
  wp.p[4] = ffW;           wp.p[5] = skW;
  wp.p[6] = qW + 16384;    wp.p[7] = kW + 16384;    wp.p[8] = vW + 16384;
  wp.p[9] = ffW + 16384;   wp.p[10] = skW + 16384;
  prep_w<<<88, 256, 0, stream>>>(wp, Wsw);
  pack_mask<<<512, 256, 0, stream>>>(mask, mbits);

  gemm_one<0><<<MTOT / 128, 256, 0, stream>>>(x, Wsw, h, stats);
  bn_apply<<<1024, 256, 0, stream>>>(h, stats, ing, inb);

  for (int l = 0; l < NLAYER; ++l) {
    const int poff = l * DIM;
    const ushort* wbase = Wsw + (1 + 5 * l) * 16384;
    float* stq = stats + (1 + 5 * l) * 256;
    float* stk = stats + (2 + 5 * l) * 256;
    float* stv = stats + (3 + 5 * l) * 256;
    float* stf = stats + (4 + 5 * l) * 256;
    float* sts = stats + (5 + 5 * l) * 256;

    gemm_qkvs<<<MTOT / 128, 256, 0, stream>>>(h, wbase, qbuf, kbuf, vbuf, sbuf,
                                              stq, stk, stv, sts);

    attn_ln<<<NBATCH, 256, 0, stream>>>(
        qbuf, kbuf, vbuf, h /* h in, out1 fp32 out (in-place) */, mbits,
        stq, stk, stv,
        qg + poff, qb + poff, kg + poff, kb + poff, vg + poff, vb + poff,
        lng + poff, lnb + poff);

    // ff_raw = gemm(out1); A fp32 row-major from h, out fp32 HEAD-MAJOR
    gemm_one<1><<<MTOT / 128, 256, 0, stream>>>(
        h, wbase + 3 * 16384, ffbuf, stf);

    if (l < NLAYER - 1) {
      fuse2_k<false><<<1024, 256, 0, stream>>>(
          h, ffbuf, sbuf, stf, sts,
          ffg + poff, ffb + poff, skg + poff, skb + poff,
          lng + poff, lnb + poff, h /* in-place */);
    } else {
      fuse2_k<true><<<64, 256, 0, stream>>>(
          h, ffbuf, sbuf, stf, sts,
          ffg + poff, ffb + poff, skg + poff, skb + poff,
          lng + poff, lnb + poff, (float*)d_out);
    }
  }
}

// Round 12
// 536.814 us; speedup vs baseline: 1.2505x; 1.2505x over previous
//
#include <hip/hip_runtime.h>
#include <hip/hip_bf16.h>

// ToyMDNN on MI355X — round 12.
//  * r11 post-mortem: __launch_bounds__(256,4) clamped VGPR to 64 -> whole
//    register state spilled to scratch (FETCH 51->162MB, WRITE 174->347MB).
//    Fix: (256,2) floor (proven no-spill), keep 40KB LDS -> HW runs 4 blk/CU
//    (LDS-limited) with full registers.
//  * numeric margin: K stored RAW FP32 head-major; normalized+rounded ONCE
//    in attn (removes one of the two double-rounding sites). Workspace 237MB.
// N=1024 S=128 D=128 H=4 C=32 L=2. GEMM biases cancel through batch-norm.

typedef __attribute__((ext_vector_type(8))) short short8v;
typedef __attribute__((ext_vector_type(16))) float f32x16;

#define NBATCH 1024
#define SEQ    128
#define DIM    128
#define NLAYER 2
#define MTOT   (NBATCH*SEQ)
#define EPSF   1e-5f
#define INV_M  (1.0f/131072.0f)
#define HM32   ((long)MTOT * 32)     // head-major per-head region (elements)

__device__ __forceinline__ float bf2f(ushort s) {
  return __uint_as_float(((uint)s) << 16);
}
__device__ __forceinline__ ushort f2bf(float f) {
  uint u = __float_as_uint(f);
  return (ushort)((u + 0x7FFFu + ((u >> 16) & 1u)) >> 16);
}

struct WPtrs { const float* p[11]; };

// ---------------------------------------------------------------------------
// One-time: 11 weight matrices fp32 -> bf16 packed in B-fragment order:
// dst[m*16384 + kc*1024 + nt*256 + ln*8 + i] = W[nt*32+ln][kc*8+i].
// ---------------------------------------------------------------------------
__global__ __launch_bounds__(256) void prep_w(WPtrs wp, ushort* __restrict__ dst)
{
  const int gid = blockIdx.x * 256 + threadIdx.x;   // 88*256 = 11*2048
  const int m = gid >> 11;
  const int rem = gid & 2047;
  const int j = rem >> 4, kc = rem & 15;
  const float* src = wp.p[m];
  float4 a = *(const float4*)(src + j * DIM + kc * 8);
  float4 b = *(const float4*)(src + j * DIM + kc * 8 + 4);
  short8v v;
  v[0] = (short)f2bf(a.x); v[1] = (short)f2bf(a.y);
  v[2] = (short)f2bf(a.z); v[3] = (short)f2bf(a.w);
  v[4] = (short)f2bf(b.x); v[5] = (short)f2bf(b.y);
  v[6] = (short)f2bf(b.z); v[7] = (short)f2bf(b.w);
  const int nt = j >> 5, ln = j & 31;
  *(short8v*)(dst + m * 16384 + kc * 1024 + nt * 256 + ln * 8) = v;
}

// ---------------------------------------------------------------------------
// One-time: pack 0/1 fp32 mask rows into 128-bit rows (uint4).
// ---------------------------------------------------------------------------
__global__ __launch_bounds__(256) void pack_mask(
    const float* __restrict__ mask, uint4* __restrict__ mb)
{
  const int lane = threadIdx.x & 63;
  const int wv   = (blockIdx.x * 256 + threadIdx.x) >> 6;
  const int NW   = gridDim.x * 4;
  for (int row = wv; row < MTOT; row += NW) {
    const float a = mask[(long)row * SEQ + lane];
    const float b = mask[(long)row * SEQ + 64 + lane];
    const unsigned long long lo = __ballot(a != 0.f);
    const unsigned long long hi = __ballot(b != 0.f);
    if (lane == 0) {
      uint4 w;
      w.x = (uint)lo; w.y = (uint)(lo >> 32);
      w.z = (uint)hi; w.w = (uint)(hi >> 32);
      mb[row] = w;
    }
  }
}

// ---------------------------------------------------------------------------
// Single GEMM: out[m][j] = sum_k A[m][k]*W[j][k] + column stats.
// W staged once into LDS. Half-tile bounce (8KB) + stats overlay -> 40KB LDS.
// OM=0: out fp32 [M][128]; OM=1: out fp32 head-major.
// ---------------------------------------------------------------------------
template<int OM>
__global__ __launch_bounds__(256, 2) void gemm_one(
    const float* __restrict__ A, const ushort* __restrict__ Wm,
    float* __restrict__ outp, float* __restrict__ stats)
{
  __shared__ ushort Wl[16384];       // 32 KB staged weights
  __shared__ float tb[4][512];       // 8 KB half-tile bounce; stats overlay
  const int tid = threadIdx.x;
  const int lane = tid & 63, wid = tid >> 6;
  const int hi = lane >> 5, ln = lane & 31;
  const long m0 = (long)blockIdx.x * 128;
  const long arow = m0 + wid * 32 + ln;

  // stage W (coalesced 16B copy)
#pragma unroll
  for (int i = 0; i < 8; ++i)
    ((short8v*)Wl)[i * 256 + tid] = ((const short8v*)Wm)[i * 256 + tid];

  short8v afr[8];
  {
    const float* ar = A + arow * DIM + hi * 8;
#pragma unroll
    for (int kt = 0; kt < 8; ++kt) {
      float4 a0 = *(const float4*)(ar + kt * 16);
      float4 a1 = *(const float4*)(ar + kt * 16 + 4);
      short8v v;
      v[0] = (short)f2bf(a0.x); v[1] = (short)f2bf(a0.y);
      v[2] = (short)f2bf(a0.z); v[3] = (short)f2bf(a0.w);
      v[4] = (short)f2bf(a1.x); v[5] = (short)f2bf(a1.y);
      v[6] = (short)f2bf(a1.z); v[7] = (short)f2bf(a1.w);
      afr[kt] = v;
    }
  }
  __syncthreads();

  f32x16 acc[4];
#pragma unroll
  for (int nt = 0; nt < 4; ++nt)
#pragma unroll
    for (int r = 0; r < 16; ++r) acc[nt][r] = 0.f;

#pragma unroll
  for (int kt = 0; kt < 8; ++kt) {
    const ushort* wb = Wl + (kt * 2 + hi) * 1024 + ln * 8;
#pragma unroll
    for (int nt = 0; nt < 4; ++nt) {
      short8v b = *(const short8v*)(wb + nt * 256);
      acc[nt] = __builtin_amdgcn_mfma_f32_32x32x16_bf16(afr[kt], b, acc[nt], 0, 0, 0);
    }
  }

  float ps[4], pq[4];
#pragma unroll
  for (int nt = 0; nt < 4; ++nt) { ps[nt] = 0.f; pq[nt] = 0.f; }

#pragma unroll
  for (int nt = 0; nt < 4; ++nt) {
#pragma unroll
    for (int h2 = 0; h2 < 2; ++h2) {      // half-tile: rows h2*16 .. +15
#pragma unroll
      for (int rr = 0; rr < 8; ++rr) {
        const int r = h2 * 8 + rr;
        const float v = acc[nt][r];
        ps[nt] += v; pq[nt] += v * v;
        const int lrow = (rr & 3) + 8 * (rr >> 2) + 4 * hi;   // 0..15
        tb[wid][lrow * 32 + ln] = v;
      }
      if constexpr (OM == 0) {
#pragma unroll
        for (int i = 0; i < 2; ++i) {
          const int lrow = i * 8 + (lane >> 3);
          float4 v = *(const float4*)&tb[wid][lrow * 32 + (lane & 7) * 4];
          *(float4*)(outp + (m0 + wid * 32 + h2 * 16 + lrow) * DIM + nt * 32 + (lane & 7) * 4) = v;
        }
      } else {
        float* dst = outp + (long)nt * HM32 + (m0 + wid * 32 + h2 * 16) * 32;
#pragma unroll
        for (int i = 0; i < 2; ++i) {
          float4 v = *(const float4*)&tb[wid][i * 256 + lane * 4];
          *(float4*)(dst + i * 256 + lane * 4) = v;
        }
      }
    }
  }

#pragma unroll
  for (int nt = 0; nt < 4; ++nt) {
    ps[nt] += __shfl_xor(ps[nt], 32);
    pq[nt] += __shfl_xor(pq[nt], 32);
  }
  // stats overlay on tb (256 floats)
  float* cs = (float*)tb;
  __syncthreads();
  if (tid < 256) cs[tid] = 0.f;
  __syncthreads();
  if (hi == 0) {
#pragma unroll
    for (int nt = 0; nt < 4; ++nt) {
      atomicAdd(&cs[nt * 32 + ln], ps[nt]);
      atomicAdd(&cs[128 + nt * 32 + ln], pq[nt]);
    }
  }
  __syncthreads();
  if (tid < 128) {
    atomicAdd(&stats[tid],       cs[tid]);
    atomicAdd(&stats[128 + tid], cs[128 + tid]);
  }
}

// ---------------------------------------------------------------------------
// Fused Q/K/V/SKIP GEMM. A read once; weights pipelined through a 2x16KB
// HALF-matrix LDS dbuf (reg-prefetch next half before MFMA, write into the
// other buffer, 1 barrier/stage; 8 stages x 16 MFMA). q/v/skip bf16
// head-major; K FP32 head-major (single-rounding path). LDS 40KB.
// ---------------------------------------------------------------------------
__global__ __launch_bounds__(256, 2) void gemm_qkvs(
    const float* __restrict__ A, const ushort* __restrict__ wbase,
    ushort* __restrict__ o0, float* __restrict__ o1,
    ushort* __restrict__ o2, ushort* __restrict__ o3,
    float* __restrict__ st0, float* __restrict__ st1,
    float* __restrict__ st2, float* __restrict__ st3)
{
  __shared__ ushort wbuf[2][8192];       // 2 x 16KB half-matrix dbuf
  __shared__ ushort qtb[4][1024];        // 8KB bounce (bf16/fp32-half/stats)
  const int tid = threadIdx.x;
  const int lane = tid & 63, wid = tid >> 6;
  const int hi = lane >> 5, ln = lane & 31;
  const long m0 = (long)blockIdx.x * 128;
  const long arow = m0 + wid * 32 + ln;

  short8v afr[8];
  {
    const float* ar = A + arow * DIM + hi * 8;
#pragma unroll
    for (int kt = 0; kt < 8; ++kt) {
      float4 a0 = *(const float4*)(ar + kt * 16);
      float4 a1 = *(const float4*)(ar + kt * 16 + 4);
      short8v v;
      v[0] = (short)f2bf(a0.x); v[1] = (short)f2bf(a0.y);
      v[2] = (short)f2bf(a0.z); v[3] = (short)f2bf(a0.w);
      v[4] = (short)f2bf(a1.x); v[5] = (short)f2bf(a1.y);
      v[6] = (short)f2bf(a1.z); v[7] = (short)f2bf(a1.w);
      afr[kt] = v;
    }
  }

  // stage half 0 of w0
#pragma unroll
  for (int i = 0; i < 4; ++i)
    ((short8v*)wbuf[0])[i * 256 + tid] = ((const short8v*)wbase)[i * 256 + tid];

  float ps[4][4], pq[4][4];
#pragma unroll
  for (int w = 0; w < 4; ++w)
#pragma unroll
    for (int nt = 0; nt < 4; ++nt) { ps[w][nt] = 0.f; pq[w][nt] = 0.f; }

  f32x16 acc[4];
  __syncthreads();

#pragma unroll
  for (int s = 0; s < 8; ++s) {
    const int w = s >> 1, half = s & 1;
    constexpr int wofl[4] = {0, 1, 2, 4};      // q,k,v,skip matrix offsets

    // prefetch next half-matrix into registers (global loads issue now)
    short8v nw[4];
    if (s < 7) {
      const int ns = s + 1;
      const short8v* src = (const short8v*)(wbase + wofl[ns >> 1] * 16384 + (ns & 1) * 8192);
#pragma unroll
      for (int i = 0; i < 4; ++i) nw[i] = src[i * 256 + tid];
    }

    if (half == 0) {
#pragma unroll
      for (int nt = 0; nt < 4; ++nt)
#pragma unroll
        for (int r = 0; r < 16; ++r) acc[nt][r] = 0.f;
    }

    const ushort* wt = wbuf[s & 1];
#pragma unroll
    for (int ktl = 0; ktl < 4; ++ktl) {
      const int kt = half * 4 + ktl;
      const ushort* wb = wt + (ktl * 2 + hi) * 1024 + ln * 8;
#pragma unroll
      for (int nt = 0; nt < 4; ++nt) {
        short8v b = *(const short8v*)(wb + nt * 256);
        acc[nt] = __builtin_amdgcn_mfma_f32_32x32x16_bf16(afr[kt], b, acc[nt], 0, 0, 0);
      }
    }

    // write prefetched half into the OTHER buffer (readers done last stage)
    if (s < 7) {
      short8v* dst = (short8v*)wbuf[(s + 1) & 1];
#pragma unroll
      for (int i = 0; i < 4; ++i) dst[i * 256 + tid] = nw[i];
    }

    if (half == 1) {
      if (w == 1) {
        // K: FP32 head-major via fp32 half-tile bounce (union with qtb)
        float* ftb = (float*)&qtb[wid][0];       // 512 floats per wave
#pragma unroll
        for (int nt = 0; nt < 4; ++nt) {
#pragma unroll
          for (int h2 = 0; h2 < 2; ++h2) {
#pragma unroll
            for (int rr = 0; rr < 8; ++rr) {
              const int r = h2 * 8 + rr;
              const float v = acc[nt][r];
              ps[1][nt] += v; pq[1][nt] += v * v;
              const int lrow = (rr & 3) + 8 * (rr >> 2) + 4 * hi;
              ftb[lrow * 32 + ln] = v;
            }
            float* dst = o1 + (long)nt * HM32 + (m0 + wid * 32 + h2 * 16) * 32;
#pragma unroll
            for (int i = 0; i < 2; ++i) {
              float4 v = *(const float4*)&ftb[i * 256 + lane * 4];
              *(float4*)(dst + i * 256 + lane * 4) = v;
            }
          }
        }
      } else {
        ushort* outp = (w == 0) ? o0 : (w == 2) ? o2 : o3;
#pragma unroll
        for (int nt = 0; nt < 4; ++nt) {
#pragma unroll
          for (int r = 0; r < 16; ++r) {
            const float v = acc[nt][r];
            ps[w][nt] += v; pq[w][nt] += v * v;
            const int row = (r & 3) + 8 * (r >> 2) + 4 * hi;
            qtb[wid][row * 32 + ln] = f2bf(v);
          }
          ushort* dst = outp + (long)nt * HM32 + (m0 + wid * 32) * 32;
          short8v v0 = *(const short8v*)&qtb[wid][lane * 8];
          short8v v1 = *(const short8v*)&qtb[wid][512 + lane * 8];
          *(short8v*)(dst + lane * 8)       = v0;
          *(short8v*)(dst + 512 + lane * 8) = v1;
        }
      }
    }
    __syncthreads();
  }

  // stats epilogue, overlaid on qtb
  float* cs = (float*)qtb;
  cs[tid] = 0.f; cs[256 + tid] = 0.f; cs[512 + tid] = 0.f; cs[768 + tid] = 0.f;
  __syncthreads();
#pragma unroll
  for (int w = 0; w < 4; ++w) {
    float lps[4], lpq[4];
#pragma unroll
    for (int nt = 0; nt < 4; ++nt) {
      lps[nt] = ps[w][nt] + __shfl_xor(ps[w][nt], 32);
      lpq[nt] = pq[w][nt] + __shfl_xor(pq[w][nt], 32);
    }
    if (hi == 0) {
#pragma unroll
      for (int nt = 0; nt < 4; ++nt) {
        atomicAdd(&cs[w * 256 + nt * 32 + ln], lps[nt]);
        atomicAdd(&cs[w * 256 + 128 + nt * 32 + ln], lpq[nt]);
      }
    }
  }
  __syncthreads();
  if (tid < 128) {
    atomicAdd(&st0[tid],       cs[tid]);
    atomicAdd(&st0[128 + tid], cs[128 + tid]);
    atomicAdd(&st1[tid],       cs[256 + tid]);
    atomicAdd(&st1[128 + tid], cs[384 + tid]);
    atomicAdd(&st2[tid],       cs[512 + tid]);
    atomicAdd(&st2[128 + tid], cs[640 + tid]);
    atomicAdd(&st3[tid],       cs[768 + tid]);
    atomicAdd(&st3[128 + tid], cs[896 + tid]);
  }
}

// ---------------------------------------------------------------------------
// In-place BN apply for h (fp32).
// ---------------------------------------------------------------------------
__global__ __launch_bounds__(256) void bn_apply(
    float* __restrict__ x, const float* __restrict__ st,
    const float* __restrict__ g, const float* __restrict__ b)
{
  __shared__ float sc[128], bi[128];
  const int tid = threadIdx.x;
  if (tid < 128) {
    float mean = st[tid] * INV_M;
    float var  = st[128 + tid] * INV_M - mean * mean;
    float s = rsqrtf(var + EPSF) * g[tid];
    sc[tid] = s;
    bi[tid] = b[tid] - mean * s;
  }
  __syncthreads();
  const long total4 = (long)MTOT * DIM / 4;
  for (long i = (long)blockIdx.x * 256 + tid; i < total4; i += (long)gridDim.x * 256) {
    float4 vv = ((const float4*)x)[i];
    const int c = (int)((i * 4) & 127);
    vv.x = vv.x * sc[c + 0] + bi[c + 0];
    vv.y = vv.y * sc[c + 1] + bi[c + 1];
    vv.z = vv.z * sc[c + 2] + bi[c + 2];
    vv.w = vv.w * sc[c + 3] + bi[c + 3];
    ((float4*)x)[i] = vv;
  }
}

// ---------------------------------------------------------------------------
// Attention + fused LN(agg+h). One block per n; wave = head.
// K raw FP32 (normalized + rounded ONCE here). S^T = mfma(K,Q) -> in-lane
// softmax; PV from D-regs; V BN folded via sum(P)=1; y = vs*o+vb0 + h (fp32);
// LN across waves via LDS reduce; out1 FP32 IN-PLACE over h ([M][128]).
// ---------------------------------------------------------------------------
__global__ __launch_bounds__(256, 4) void attn_ln(
    const ushort* __restrict__ q, const float* __restrict__ k_in,
    const ushort* __restrict__ v_in,
    float* hbuf,                      // h in, out1 out (aliased on purpose)
    const uint4* __restrict__ mb,
    const float* __restrict__ qst, const float* __restrict__ kst, const float* __restrict__ vst,
    const float* __restrict__ qg, const float* __restrict__ qbb,
    const float* __restrict__ kg, const float* __restrict__ kbb,
    const float* __restrict__ vg, const float* __restrict__ vbb,
    const float* __restrict__ lng, const float* __restrict__ lnb)
{
  __shared__ ushort Vp[128 * 136];          // [c_global][slot(t)]
  __shared__ float qsc[128], qbi[128], ksc[128], kbi[128];
  __shared__ float reds[32][4], redq[32][4];
  __shared__ float2 rmv[32];

  const int tid = threadIdx.x;
  const int lane = tid & 63, hh = tid >> 6;
  const int hi = lane >> 5, ln = lane & 31;
  const int n = blockIdx.x;
  const long nb = (long)n * SEQ;            // global row base
  const long hbase = (long)hh * HM32 + nb * 32;

  if (tid < 128) {
    const int c = tid;
    float m, v, s;
    m = qst[c] * INV_M; v = qst[128 + c] * INV_M - m * m;
    s = rsqrtf(v + EPSF) * qg[c];  qsc[c] = s; qbi[c] = qbb[c] - m * s;
    m = kst[c] * INV_M; v = kst[128 + c] * INV_M - m * m;
    s = rsqrtf(v + EPSF) * kg[c];  ksc[c] = s; kbi[c] = kbb[c] - m * s;
  }
  const int cg = hh * 32 + ln;              // global output column
  float vs, vb0;
  {
    float m = vst[cg] * INV_M;
    float v = vst[128 + cg] * INV_M - m * m;
    vs = rsqrtf(v + EPSF) * vg[cg];
    vb0 = vbb[cg] - m * vs;
  }
  const float lgc = lng[cg], lbc = lnb[cg];

  // stage own head's V slice (dense 8KB) into permuted slots
#pragma unroll
  for (int it = 0; it < 8; ++it) {
    const int t = it * 16 + (lane >> 2);
    const int c0 = (lane & 3) * 8;
    short8v vv = *(const short8v*)(v_in + hbase + (long)t * 32 + c0);
    const int tl = t & 31;
    const int kt = tl >> 4;
    const int rem = tl & 15;
    const int slot = (t & 96) + (kt << 4) + ((rem >> 2) & 1) * 8 + ((rem & 3) | (((rem >> 3) & 1) << 2));
#pragma unroll
    for (int i = 0; i < 8; ++i) Vp[(hh * 32 + c0 + i) * 136 + slot] = (ushort)vv[i];
  }
  __syncthreads();

  // normalized K fragments from RAW FP32 (single rounding), cached
  short8v kfr[4][2];
#pragma unroll
  for (int nt = 0; nt < 4; ++nt)
#pragma unroll
    for (int kt = 0; kt < 2; ++kt) {
      const float* kr = k_in + hbase + (long)(nt * 32 + ln) * 32 + kt * 16 + hi * 8;
      float4 a0 = *(const float4*)kr;
      float4 a1 = *(const float4*)(kr + 4);
      const int c0 = hh * 32 + kt * 16 + hi * 8;
      short8v f;
      f[0] = (short)f2bf(a0.x * ksc[c0 + 0] + kbi[c0 + 0]);
      f[1] = (short)f2bf(a0.y * ksc[c0 + 1] + kbi[c0 + 1]);
      f[2] = (short)f2bf(a0.z * ksc[c0 + 2] + kbi[c0 + 2]);
      f[3] = (short)f2bf(a0.w * ksc[c0 + 3] + kbi[c0 + 3]);
      f[4] = (short)f2bf(a1.x * ksc[c0 + 4] + kbi[c0 + 4]);
      f[5] = (short)f2bf(a1.y * ksc[c0 + 5] + kbi[c0 + 5]);
      f[6] = (short)f2bf(a1.z * ksc[c0 + 6] + kbi[c0 + 6]);
      f[7] = (short)f2bf(a1.w * ksc[c0 + 7] + kbi[c0 + 7]);
      kfr[nt][kt] = f;
    }

  for (int mt = 0; mt < 4; ++mt) {
    // normalized Q fragments (B operand): col s = mt*32+ln
    short8v qfr[2];
#pragma unroll
    for (int kt = 0; kt < 2; ++kt) {
      short8v raw = *(const short8v*)(q + hbase + (long)(mt * 32 + ln) * 32 + kt * 16 + hi * 8);
      short8v f;
#pragma unroll
      for (int i = 0; i < 8; ++i) {
        const int c = hh * 32 + kt * 16 + hi * 8 + i;
        f[i] = (short)f2bf(bf2f((ushort)raw[i]) * qsc[c] + qbi[c]);
      }
      qfr[kt] = f;
    }

    f32x16 st[4];
#pragma unroll
    for (int nt = 0; nt < 4; ++nt)
#pragma unroll
      for (int r = 0; r < 16; ++r) st[nt][r] = 0.f;
#pragma unroll
    for (int nt = 0; nt < 4; ++nt) {
      st[nt] = __builtin_amdgcn_mfma_f32_32x32x16_bf16(kfr[nt][0], qfr[0], st[nt], 0, 0, 0);
      st[nt] = __builtin_amdgcn_mfma_f32_32x32x16_bf16(kfr[nt][1], qfr[1], st[nt], 0, 0, 0);
    }

    // mask + in-lane softmax (softmax(alpha*mask) semantics)
    const uint4 bw = mb[nb + mt * 32 + ln];
    float mx = -1e30f;
#pragma unroll
    for (int nt = 0; nt < 4; ++nt) {
      const uint word = (nt == 0) ? bw.x : (nt == 1) ? bw.y : (nt == 2) ? bw.z : bw.w;
#pragma unroll
      for (int r = 0; r < 16; ++r) {
        const int crow = (r & 3) + 8 * (r >> 2) + 4 * hi;
        st[nt][r] = ((word >> crow) & 1u) ? st[nt][r] : 0.f;
        mx = fmaxf(mx, st[nt][r]);
      }
    }
    mx = fmaxf(mx, __shfl_xor(mx, 32));
    float sum = 0.f;
#pragma unroll
    for (int nt = 0; nt < 4; ++nt)
#pragma unroll
      for (int r = 0; r < 16; ++r) {
        const float e = __expf(st[nt][r] - mx);
        st[nt][r] = e;
        sum += e;
      }
    sum += __shfl_xor(sum, 32);
    const float inv = 1.f / sum;

    // O = P · V_raw
    f32x16 o;
#pragma unroll
    for (int r = 0; r < 16; ++r) o[r] = 0.f;
#pragma unroll
    for (int nt = 0; nt < 4; ++nt) {
#pragma unroll
      for (int kt = 0; kt < 2; ++kt) {
        short8v pa;
#pragma unroll
        for (int j = 0; j < 8; ++j) pa[j] = (short)f2bf(st[nt][kt * 8 + j] * inv);
        short8v vb = *(const short8v*)&Vp[(long)cg * 136 + nt * 32 + kt * 16 + hi * 8];
        o = __builtin_amdgcn_mfma_f32_32x32x16_bf16(pa, vb, o, 0, 0, 0);
      }
    }

    // y = BN_v-folded agg + h  (fp32)
    float yv[16];
#pragma unroll
    for (int r = 0; r < 16; ++r) {
      const int sl = (r & 3) + 8 * (r >> 2) + 4 * hi;
      const float hval = hbuf[(nb + mt * 32 + sl) * DIM + cg];
      yv[r] = vs * o[r] + vb0 + hval;
    }

    // LN across full row: intra-half butterfly + cross-wave LDS reduce
#pragma unroll
    for (int r = 0; r < 16; ++r) {
      float s = yv[r], q2 = yv[r] * yv[r];
      s += __shfl_xor(s, 1);  q2 += __shfl_xor(q2, 1);
      s += __shfl_xor(s, 2);  q2 += __shfl_xor(q2, 2);
      s += __shfl_xor(s, 4);  q2 += __shfl_xor(q2, 4);
      s += __shfl_xor(s, 8);  q2 += __shfl_xor(q2, 8);
      s += __shfl_xor(s, 16); q2 += __shfl_xor(q2, 16);
      if (ln == 0) {
        const int sl = (r & 3) + 8 * (r >> 2) + 4 * hi;
        reds[sl][hh] = s; redq[sl][hh] = q2;
      }
    }
    __syncthreads();
    if (tid < 32) {
      const float s  = reds[tid][0] + reds[tid][1] + reds[tid][2] + reds[tid][3];
      const float q2 = redq[tid][0] + redq[tid][1] + redq[tid][2] + redq[tid][3];
      const float mean = s * (1.f / 128.f);
      const float var  = q2 * (1.f / 128.f) - mean * mean;
      rmv[tid] = make_float2(mean, rsqrtf(var + EPSF));
    }
    __syncthreads();
    // out1 fp32 in-place over h
#pragma unroll
    for (int r = 0; r < 16; ++r) {
      const int sl = (r & 3) + 8 * (r >> 2) + 4 * hi;
      const float2 mr = rmv[sl];
      hbuf[(nb + mt * 32 + sl) * DIM + cg] = (yv[r] - mr.x) * mr.y * lgc + lbc;
    }
  }
}

// ---------------------------------------------------------------------------
// h_new = LN(out1 + BN_ff(ff_raw)) + BN_skip(skip_raw).
// t1 (out1) fp32 [M][128]; ffr fp32 HEAD-MAJOR; skr bf16 HEAD-MAJOR.
// Non-final: out == t1 (in-place). FINAL: rows m=n*S -> d_out (N,128).
// ---------------------------------------------------------------------------
template <bool FINAL>
__global__ __launch_bounds__(256) void fuse2_k(
    const float* t1, const float* __restrict__ ffr, const ushort* __restrict__ skr,
    const float* __restrict__ fst, const float* __restrict__ sst,
    const float* __restrict__ fg, const float* __restrict__ fb,
    const float* __restrict__ sg, const float* __restrict__ sb,
    const float* __restrict__ lg, const float* __restrict__ lb,
    float* out)
{
  const int lane = threadIdx.x & 63;
  const int c = lane * 2;
  float fs0, fbias0, fs1, fbias1, ss0, sbias0, ss1, sbias1;
  {
    float m0 = fst[c] * INV_M;
    float v0 = fst[128 + c] * INV_M - m0 * m0;
    fs0 = rsqrtf(v0 + EPSF) * fg[c];       fbias0 = fb[c] - m0 * fs0;
    float m1 = fst[c + 1] * INV_M;
    float v1 = fst[128 + c + 1] * INV_M - m1 * m1;
    fs1 = rsqrtf(v1 + EPSF) * fg[c + 1];   fbias1 = fb[c + 1] - m1 * fs1;
    float n0 = sst[c] * INV_M;
    float w0 = sst[128 + c] * INV_M - n0 * n0;
    ss0 = rsqrtf(w0 + EPSF) * sg[c];       sbias0 = sb[c] - n0 * ss0;
    float n1 = sst[c + 1] * INV_M;
    float w1 = sst[128 + c + 1] * INV_M - n1 * n1;
    ss1 = rsqrtf(w1 + EPSF) * sg[c + 1];   sbias1 = sb[c + 1] - n1 * ss1;
  }
  const float lg0 = lg[c], lg1 = lg[c + 1], lb0 = lb[c], lb1 = lb[c + 1];
  const int wid = (blockIdx.x * 256 + threadIdx.x) >> 6;
  const int NW  = gridDim.x * 4;
  const int ROWS = FINAL ? NBATCH : MTOT;
  const long thm = (long)(c >> 5) * HM32;       // head region of cols c, c+1
  for (int r = wid; r < ROWS; r += NW) {
    const long m   = FINAL ? (long)r * SEQ : (long)r;
    const long off = m * DIM + c;
    const long hm  = thm + m * 32 + (c & 31);
    float2 tv = *(const float2*)(t1 + off);
    float2 fv = *(const float2*)(ffr + hm);
    uint sv = *(const uint*)(skr + hm);
    float s0 = bf2f((ushort)(sv & 0xFFFFu)), s1 = bf2f((ushort)(sv >> 16));
    float y0 = tv.x + fv.x * fs0 + fbias0;
    float y1 = tv.y + fv.y * fs1 + fbias1;
    float s = y0 + y1, sq = y0 * y0 + y1 * y1;
#pragma unroll
    for (int o = 32; o; o >>= 1) { s += __shfl_xor(s, o); sq += __shfl_xor(sq, o); }
    const float mean = s * (1.f / 128.f);
    const float var  = sq * (1.f / 128.f) - mean * mean;
    const float rs   = rsqrtf(var + EPSF);
    float o0 = (y0 - mean) * rs * lg0 + lb0 + (s0 * ss0 + sbias0);
    float o1 = (y1 - mean) * rs * lg1 + lb1 + (s1 * ss1 + sbias1);
    const long ooff = FINAL ? ((long)r * DIM + c) : off;
    *(float2*)(out + ooff) = make_float2(o0, o1);
  }
}

// ---------------------------------------------------------------------------
extern "C" void kernel_launch(void* const* d_in, const int* in_sizes, int n_in,
                              void* d_out, int out_size, void* d_ws, size_t ws_size,
                              hipStream_t stream)
{
  (void)in_sizes; (void)n_in; (void)out_size; (void)ws_size;
  const float* x    = (const float*)d_in[0];
  const float* mask = (const float*)d_in[1];
  const float* linW = (const float*)d_in[2];
  const float* ing  = (const float*)d_in[4];
  const float* inb  = (const float*)d_in[5];
  const float* qW   = (const float*)d_in[6];
  const float* qg   = (const float*)d_in[8];
  const float* qb   = (const float*)d_in[9];
  const float* kW   = (const float*)d_in[10];
  const float* kg   = (const float*)d_in[12];
  const float* kb   = (const float*)d_in[13];
  const float* vW   = (const float*)d_in[14];
  const float* vg   = (const float*)d_in[16];
  const float* vb   = (const float*)d_in[17];
  const float* lng  = (const float*)d_in[18];
  const float* lnb  = (const float*)d_in[19];
  const float* ffW  = (const float*)d_in[20];
  const float* ffg  = (const float*)d_in[22];
  const float* ffb  = (const float*)d_in[23];
  const float* skW  = (const float*)d_in[24];
  const float* skg  = (const float*)d_in[26];
  const float* skb  = (const float*)d_in[27];

  const long MD = (long)MTOT * DIM;
  float*  stats = (float*)d_ws;                 // 11*256 floats
  float*  h     = (float*)d_ws + 4096;          // fp32 [M][128]; out1/h_next
  float*  kf    = h + MD;                       // fp32 head-major K raw
  ushort* qbuf  = (ushort*)(kf + MD);           // bf16 head-major q
  ushort* vbuf  = qbuf + MD;                    // bf16 head-major v
  ushort* sbuf  = vbuf + MD;                    // bf16 head-major skip_raw
  uint4*  mbits = (uint4*)(sbuf + MD);          // 2 MB; total ~237 MB
  float*  ffbuf = (float*)qbuf;                 // fp32 ff over dead q+v (64MB)

  ushort* Wsw = (ushort*)d_out;                 // 352 KB of 512 KB; final
                                                // fuse2<true> overwrites all.
  hipMemsetAsync(stats, 0, 11 * 256 * sizeof(float), stream);

  WPtrs wp;
  wp.p[0] = linW;
  wp.p[1] = qW;            wp.p[2] = kW;            wp.p[3] = vW;
  wp.p[4] = ffW;           wp.p[5] = skW;
  wp.p[6] = qW + 16384;    wp.p[7] = kW + 16384;    wp.p[8] = vW + 16384;
  wp.p[9] = ffW + 16384;   wp.p[10] = skW + 16384;
  prep_w<<<88, 256, 0, stream>>>(wp, Wsw);
  pack_mask<<<512, 256, 0, stream>>>(mask, mbits);

  gemm_one<0><<<MTOT / 128, 256, 0, stream>>>(x, Wsw, h, stats);
  bn_apply<<<1024, 256, 0, stream>>>(h, stats, ing, inb);

  for (int l = 0; l < NLAYER; ++l) {
    const int poff = l * DIM;
    const ushort* wbase = Wsw + (1 + 5 * l) * 16384;
    float* stq = stats + (1 + 5 * l) * 256;
    float* stk = stats + (2 + 5 * l) * 256;
    float* stv = stats + (3 + 5 * l) * 256;
    float* stf = stats + (4 + 5 * l) * 256;
    float* sts = stats + (5 + 5 * l) * 256;

    gemm_qkvs<<<MTOT / 128, 256, 0, stream>>>(h, wbase, qbuf, kf, vbuf, sbuf,
                                              stq, stk, stv, sts);

    attn_ln<<<NBATCH, 256, 0, stream>>>(
        qbuf, kf, vbuf, h /* h in, out1 fp32 out (in-place) */, mbits,
        stq, stk, stv,
        qg + poff, qb + poff, kg + poff, kb + poff, vg + poff, vb + poff,
        lng + poff, lnb + poff);

    // ff_raw = gemm(out1); A fp32 row-major from h, out fp32 HEAD-MAJOR
    gemm_one<1><<<MTOT / 128, 256, 0, stream>>>(
        h, wbase + 3 * 16384, ffbuf, stf);

    if (l < NLAYER - 1) {
      fuse2_k<false><<<1024, 256, 0, stream>>>(
          h, ffbuf, sbuf, stf, sts,
          ffg + poff, ffb + poff, skg + poff, skb + poff,
          lng + poff, lnb + poff, h /* in-place */);
    } else {
      fuse2_k<true><<<64, 256, 0, stream>>>(
          h, ffbuf, sbuf, stf, sts,
          ffg + poff, ffb + poff, skg + poff, skb + poff,
          lng + poff, lnb + poff, (float*)d_out);
    }
  }
}